// Round 1
// baseline (485.474 us; speedup 1.0000x reference)
//
#include <hip/hip_runtime.h>
#include <math.h>

// ForwardKinematics: B=524288, J=24, fp32.
// Zero-LDS version: one thread per element, AoS register-resident compute.
// Rationale: previous LDS-transpose kernel used 49.6KB LDS/128-thread block
// -> 3 blocks/CU -> 1.5 waves/SIMD (19% occupancy), latency-bound at 1.1 TB/s
// (roofline is ~66us / 6.3 TB/s). AoS loads stream fine through L1/L2 (wave
// footprint 24KB, every fetched byte consumed); scattered dword stores merge
// in L2 (per-block write window 72KB << 4MB L2). Removing LDS + per-joint
// immediate stores keeps VGPR ~120 -> ~4 waves/SIMD, no barriers.

#define NB 524288
#define NJ 24
#define BLOCK 256

namespace {
constexpr int PAR[NJ] = {-1,0,0,0,1,2,3,4,5,6,7,8,9,9,9,12,13,14,16,17,18,19,20,21};
}

__global__ __launch_bounds__(BLOCK)
void ForwardKinematics_51342039056994_kernel(
    const float* __restrict__ root_q,   // (B,4)
    const float* __restrict__ root_p,   // (B,3)
    const float* __restrict__ loc_q,    // (B,24,4)
    const float* __restrict__ bones,    // (B,24)
    const float* __restrict__ rest_d,   // (24,3)  uniform -> scalar loads
    float* __restrict__ out)            // (B,24,3)
{
    const int b = blockIdx.x * BLOCK + threadIdx.x;

    float gqw[NJ], gqx[NJ], gqy[NJ], gqz[NJ];
    float gpx[NJ], gpy[NJ], gpz[NJ];

    // ---- root: coalesced float4 quat + 3 dword position ----
    float4 rq = ((const float4*)root_q)[b];
    {
        float inv = 1.0f / (sqrtf(rq.x*rq.x + rq.y*rq.y + rq.z*rq.z + rq.w*rq.w) + 1e-8f);
        gqw[0] = rq.x * inv; gqx[0] = rq.y * inv; gqy[0] = rq.z * inv; gqz[0] = rq.w * inv;
    }
    gpx[0] = root_p[b*3+0];
    gpy[0] = root_p[b*3+1];
    gpz[0] = root_p[b*3+2];

    const float4* lsrc = (const float4*)loc_q + (size_t)b * NJ; // 24 float4 / elem
    const float4* bsrc = (const float4*)(bones + (size_t)b * NJ); // 6 float4 / elem
    float* dst = out + (size_t)b * 72;

    // root position out
    dst[0] = gpx[0]; dst[1] = gpy[0]; dst[2] = gpz[0];

    // One joint step. j is a compile-time-foldable unrolled constant, so
    // PAR[j] and all array indices fold -> everything stays in registers.
    #define DO_JOINT(j, lqv, L)                                                 \
    {                                                                           \
        const int p_ = PAR[(j)];                                                \
        float lw = (lqv).x, lx = (lqv).y, ly = (lqv).z, lz = (lqv).w;           \
        float invn = 1.0f / (sqrtf(lw*lw + lx*lx + ly*ly + lz*lz) + 1e-8f);     \
        lw *= invn; lx *= invn; ly *= invn; lz *= invn;                         \
        const float pw  = gqw[p_], px_ = gqx[p_], py_ = gqy[p_], pz_ = gqz[p_]; \
        gqw[(j)] = pw*lw - px_*lx - py_*ly - pz_*lz;                            \
        gqx[(j)] = pw*lx + px_*lw + py_*lz - pz_*ly;                            \
        gqy[(j)] = pw*ly - px_*lz + py_*lw + pz_*lx;                            \
        gqz[(j)] = pw*lz + px_*ly - py_*lx + pz_*lw;                            \
        const float dx = rest_d[3*(j)+0];                                       \
        const float dy = rest_d[3*(j)+1];                                       \
        const float dz = rest_d[3*(j)+2];                                       \
        float tx = 2.0f*(py_*dz - pz_*dy);                                      \
        float ty = 2.0f*(pz_*dx - px_*dz);                                      \
        float tz = 2.0f*(px_*dy - py_*dx);                                      \
        float rx = dx + pw*tx + (py_*tz - pz_*ty);                              \
        float ry = dy + pw*ty + (pz_*tx - px_*tz);                              \
        float rz = dz + pw*tz + (px_*ty - py_*tx);                              \
        gpx[(j)] = gpx[p_] + rx*(L);                                            \
        gpy[(j)] = gpy[p_] + ry*(L);                                            \
        gpz[(j)] = gpz[p_] + rz*(L);                                            \
        dst[3*(j)+0] = gpx[(j)];                                                \
        dst[3*(j)+1] = gpy[(j)];                                                \
        dst[3*(j)+2] = gpz[(j)];                                                \
    }

    // ---- 3 chunks of 8 joints: load 8 quats + 2 bone-float4 per chunk (MLP=10),
    // then run the serial chain for those joints, storing positions immediately.
    #pragma unroll
    for (int c = 0; c < 3; ++c) {
        float4 lq[8];
        #pragma unroll
        for (int i = 0; i < 8; ++i) lq[i] = lsrc[8*c + i];
        float4 bq0 = bsrc[2*c + 0];
        float4 bq1 = bsrc[2*c + 1];
        float bl[8] = {bq0.x, bq0.y, bq0.z, bq0.w, bq1.x, bq1.y, bq1.z, bq1.w};

        #pragma unroll
        for (int jj = 0; jj < 8; ++jj) {
            const int j = 8*c + jj;
            if (j == 0) continue;  // root handled above
            DO_JOINT(j, lq[jj], bl[jj]);
        }
    }
    #undef DO_JOINT
}

extern "C" void kernel_launch(void* const* d_in, const int* in_sizes, int n_in,
                              void* d_out, int out_size, void* d_ws, size_t ws_size,
                              hipStream_t stream) {
    (void)in_sizes; (void)n_in; (void)out_size; (void)d_ws; (void)ws_size;
    const float* root_q = (const float*)d_in[0];
    const float* root_p = (const float*)d_in[1];
    const float* loc_q  = (const float*)d_in[2];
    const float* bones  = (const float*)d_in[3];
    const float* rest_d = (const float*)d_in[4];
    float* out = (float*)d_out;

    dim3 grid(NB / BLOCK);
    dim3 block(BLOCK);
    ForwardKinematics_51342039056994_kernel<<<grid, block, 0, stream>>>(
        root_q, root_p, loc_q, bones, rest_d, out);
}

// Round 2
// 407.386 us; speedup vs baseline: 1.1917x; 1.1917x over previous
//
#include <hip/hip_runtime.h>
#include <math.h>

// ForwardKinematics: B=524288, J=24, fp32.
// v3: register compute + chunked LDS-staged coalesced stores.
// v2 (zero-LDS) showed store-side RFO: FETCH +140MB (= output size) and
// WRITE 1.9x ideal because per-lane dword stores at 72B stride partially
// touch 64B lines -> L2 write-allocate reads + multi-pass writebacks.
// Fix: stage 8 joints' positions (24 floats/elem) in a [24][257] LDS tile
// (24.7KB -> 6 blocks/CU, 75% occ) and store cooperatively as full float4
// runs (96B contiguous per element-chunk), giving near-full-line coverage.
// Next chunk's inputs are prefetched before the store phase to hide latency.

#define NB 524288
#define NJ 24
#define BLOCK 256
#define LSTR 257   // 256 cols + 1 pad: bank = (row + col) % 32, conflict-free

namespace {
constexpr int PAR[NJ] = {-1,0,0,0,1,2,3,4,5,6,7,8,9,9,9,12,13,14,16,17,18,19,20,21};
}

__global__ __launch_bounds__(BLOCK)
void ForwardKinematics_51342039056994_kernel(
    const float* __restrict__ root_q,   // (B,4)
    const float* __restrict__ root_p,   // (B,3)
    const float* __restrict__ loc_q,    // (B,24,4)
    const float* __restrict__ bones,    // (B,24)
    const float* __restrict__ rest_d,   // (24,3) uniform -> scalar loads
    float* __restrict__ out)            // (B,24,3)
{
    __shared__ float lds[24 * LSTR];    // 24,672 B: one 8-joint chunk of positions

    const int tid = threadIdx.x;
    const int blockBase = blockIdx.x * BLOCK;
    const int b = blockBase + tid;

    float gqw[NJ], gqx[NJ], gqy[NJ], gqz[NJ];
    float gpx[NJ], gpy[NJ], gpz[NJ];

    // ---- root inputs (coalesced float4 quat + 3 dwords position) ----
    float4 rq = ((const float4*)root_q)[b];
    float rpx = root_p[b*3+0], rpy = root_p[b*3+1], rpz = root_p[b*3+2];
    {
        float inv = 1.0f / (sqrtf(rq.x*rq.x + rq.y*rq.y + rq.z*rq.z + rq.w*rq.w) + 1e-8f);
        gqw[0] = rq.x * inv; gqx[0] = rq.y * inv; gqy[0] = rq.z * inv; gqz[0] = rq.w * inv;
    }
    gpx[0] = rpx; gpy[0] = rpy; gpz[0] = rpz;

    const float4* lsrc = (const float4*)loc_q + (size_t)b * NJ;   // 24 float4/elem
    const float4* bsrc = (const float4*)(bones + (size_t)b * NJ); // 6 float4/elem
    float4* outv = (float4*)out;

    // ---- prefetch chunk 0 inputs ----
    float4 lq[8];
    #pragma unroll
    for (int i = 0; i < 8; ++i) lq[i] = lsrc[i];
    float4 bq0 = bsrc[0], bq1 = bsrc[1];

    #define DO_JOINT(j, lqv, L)                                                 \
    {                                                                           \
        const int p_ = PAR[(j)];                                                \
        float lw = (lqv).x, lx = (lqv).y, ly = (lqv).z, lz = (lqv).w;           \
        float invn = 1.0f / (sqrtf(lw*lw + lx*lx + ly*ly + lz*lz) + 1e-8f);     \
        lw *= invn; lx *= invn; ly *= invn; lz *= invn;                         \
        const float pw  = gqw[p_], px_ = gqx[p_], py_ = gqy[p_], pz_ = gqz[p_]; \
        gqw[(j)] = pw*lw - px_*lx - py_*ly - pz_*lz;                            \
        gqx[(j)] = pw*lx + px_*lw + py_*lz - pz_*ly;                            \
        gqy[(j)] = pw*ly - px_*lz + py_*lw + pz_*lx;                            \
        gqz[(j)] = pw*lz + px_*ly - py_*lx + pz_*lw;                            \
        const float dx = rest_d[3*(j)+0];                                       \
        const float dy = rest_d[3*(j)+1];                                       \
        const float dz = rest_d[3*(j)+2];                                       \
        float tx = 2.0f*(py_*dz - pz_*dy);                                      \
        float ty = 2.0f*(pz_*dx - px_*dz);                                      \
        float tz = 2.0f*(px_*dy - py_*dx);                                      \
        float rx = dx + pw*tx + (py_*tz - pz_*ty);                              \
        float ry = dy + pw*ty + (pz_*tx - px_*tz);                              \
        float rz = dz + pw*tz + (px_*ty - py_*tx);                              \
        gpx[(j)] = gpx[p_] + rx*(L);                                            \
        gpy[(j)] = gpy[p_] + ry*(L);                                            \
        gpz[(j)] = gpz[p_] + rz*(L);                                            \
    }

    #pragma unroll
    for (int c = 0; c < 3; ++c) {
        // ---- prefetch next chunk inputs (latency hidden by compute+store) ----
        float4 nlq[8]; float4 nb0, nb1;
        if (c < 2) {
            #pragma unroll
            for (int i = 0; i < 8; ++i) nlq[i] = lsrc[8*(c+1) + i];
            nb0 = bsrc[2*(c+1) + 0];
            nb1 = bsrc[2*(c+1) + 1];
        }

        float bl[8] = {bq0.x, bq0.y, bq0.z, bq0.w, bq1.x, bq1.y, bq1.z, bq1.w};

        // ---- compute 8 joints + stage positions: row = (j%8)*3+comp, col = tid ----
        #pragma unroll
        for (int jj = 0; jj < 8; ++jj) {
            const int j = 8*c + jj;
            if (j > 0) DO_JOINT(j, lq[jj], bl[jj]);
            lds[(jj*3 + 0) * LSTR + tid] = gpx[j];
            lds[(jj*3 + 1) * LSTR + tid] = gpy[j];
            lds[(jj*3 + 2) * LSTR + tid] = gpz[j];
        }

        __syncthreads();

        // ---- cooperative store: 256 elems * 24 floats = 1536 float4, 6/thread.
        // Element t's chunk bytes are 96B contiguous at (blockBase+t)*288 + c*96,
        // 16B-aligned; wave covers dense 96B runs -> full-line writes. ----
        #pragma unroll
        for (int m = 0; m < 6; ++m) {
            int g = m * BLOCK + tid;
            int t = g / 6;
            int k = g - 6 * t;          // 0..5
            float4 v;
            v.x = lds[(4*k + 0) * LSTR + t];
            v.y = lds[(4*k + 1) * LSTR + t];
            v.z = lds[(4*k + 2) * LSTR + t];
            v.w = lds[(4*k + 3) * LSTR + t];
            outv[(size_t)(blockBase + t) * 18 + c * 6 + k] = v;
        }

        __syncthreads();   // protect LDS reuse by next chunk's staging

        if (c < 2) {
            #pragma unroll
            for (int i = 0; i < 8; ++i) lq[i] = nlq[i];
            bq0 = nb0; bq1 = nb1;
        }
    }
    #undef DO_JOINT
}

extern "C" void kernel_launch(void* const* d_in, const int* in_sizes, int n_in,
                              void* d_out, int out_size, void* d_ws, size_t ws_size,
                              hipStream_t stream) {
    (void)in_sizes; (void)n_in; (void)out_size; (void)d_ws; (void)ws_size;
    const float* root_q = (const float*)d_in[0];
    const float* root_p = (const float*)d_in[1];
    const float* loc_q  = (const float*)d_in[2];
    const float* bones  = (const float*)d_in[3];
    const float* rest_d = (const float*)d_in[4];
    float* out = (float*)d_out;

    dim3 grid(NB / BLOCK);
    dim3 block(BLOCK);
    ForwardKinematics_51342039056994_kernel<<<grid, block, 0, stream>>>(
        root_q, root_p, loc_q, bones, rest_d, out);
}